// Round 7
// baseline (474.687 us; speedup 1.0000x reference)
//
#include <hip/hip_runtime.h>

// SoftDTW forward, B=64, T=1024, D=8, gamma=1.0, out = mean over batch of R[T,T].
//
// R7: latency-hiding restructure. R6 post-mortem: period 1111 cyc/step =
// 498 issue (matches VALUBusy) + ~610 exposed chain/shuffle latency at
// 1 wave/SIMD. Changes:
//  - software-pipelined dots: step s consumes dots(s) computed at s-1,
//    computes dots(s+1) from tile regs loaded at s-1, prefetches tile s+2.
//    The independent pk_fma work fills the softmin-chain stall.
//  - CT=4 (4x4 cells/thread/step): NQ=256, effective steps ~535 (was 767);
//    issue/step ~830 cyc now covers the 7-softmin chain.
//  - pred operands via op_sel broadcast on v_pk_fma_f32 (halves pred regs).
//  - 4 waves (256 thr), r=4 rows/thread; sync protocol identical to R4-R6,
//    granularity 8.

typedef float v2f __attribute__((ext_vector_type(2)));

static constexpr int T      = 1024;
static constexpr int NB     = 64;
static constexpr int NTH    = 256;       // 4 waves
static constexpr int NW     = 4;
static constexpr int CT     = 4;
static constexpr int NQ     = T / CT;    // 256 col-tiles
static constexpr int WSTEPS = NQ + 63;   // 319 per-wave staircase steps

#define BIGF 1e10f
#define L2EF 1.4426950408889634f
#define LN2F 0.6931471805599453f

__device__ __forceinline__ float fexp2(float x) { return __builtin_amdgcn_exp2f(x); }
__device__ __forceinline__ float flog2(float x) { return __builtin_amdgcn_logf(x); }

// softmin in base-2 domain, 3 trans: m - log2(1 + 2^(m-med) + 2^(m-max)).
__device__ __forceinline__ float softmin2(float a, float b, float c) {
  float m = fminf(fminf(a, b), c);
  float M = fmaxf(fmaxf(a, b), c);
  float e = __builtin_amdgcn_fmed3f(a, b, c);
  float s = fexp2(m - e) + fexp2(m - M);
  return m - flog2(1.0f + s);
}

// packed fma with src0 broadcast (op_sel): lo variant uses src0.lo for both
// result halves, hi variant uses src0.hi. Saves duplicated pred registers.
__device__ __forceinline__ v2f pkfma_lo(v2f a, v2f b, v2f c) {
  v2f d;
  asm("v_pk_fma_f32 %0, %1, %2, %3 op_sel:[0,0,0] op_sel_hi:[0,1,1]"
      : "=v"(d) : "v"(a), "v"(b), "v"(c));
  return d;
}
__device__ __forceinline__ v2f pkfma_hi(v2f a, v2f b, v2f c) {
  v2f d;
  asm("v_pk_fma_f32 %0, %1, %2, %3 op_sel:[1,0,0] op_sel_hi:[1,1,1]"
      : "=v"(d) : "v"(a), "v"(b), "v"(c));
  return d;
}

__device__ __forceinline__ v2f lo2(const float4& c) { v2f r; r.x = c.x; r.y = c.y; return r; }
__device__ __forceinline__ v2f hi2(const float4& c) { v2f r; r.x = c.z; r.y = c.w; return r; }

// dot over 8 dims for one pred row (4 pairs Pp) vs tile chunks TN[0..7]
// (TN[m] = dim m over 4 cols, pre-scaled by -2*log2e). HI selects cols 2,3.
template <bool HI>
__device__ __forceinline__ v2f dot8h(v2f acc, const v2f* Pp, const float4* TN) {
#define CH(m) (HI ? hi2(TN[m]) : lo2(TN[m]))
  acc = pkfma_lo(Pp[0], CH(0), acc);
  acc = pkfma_hi(Pp[0], CH(1), acc);
  acc = pkfma_lo(Pp[1], CH(2), acc);
  acc = pkfma_hi(Pp[1], CH(3), acc);
  acc = pkfma_lo(Pp[2], CH(4), acc);
  acc = pkfma_hi(Pp[2], CH(5), acc);
  acc = pkfma_lo(Pp[3], CH(6), acc);
  acc = pkfma_hi(Pp[3], CH(7), acc);
#undef CH
  return acc;
}

// One staircase step. TC: tile(s) regs (dead -> prefetch dest for tile s+2);
// TN: tile(s+1) regs (dot source); DC: dots(s) (consumed); DN: dots(s+1).
#define STEP(SW, TC, TN, DC, DN)                                             \
  {                                                                          \
    const int sw_ = (SW);                                                    \
    if (w > 0 && sw_ < NQ && (sw_ & 7) == 0) {                               \
      const int need = ((sw_ + 7 < NQ) ? sw_ + 7 : NQ - 1) + 63;             \
      while (seen < need) {                                                   \
        seen = __hip_atomic_load(&prog_s[w - 1], __ATOMIC_ACQUIRE,           \
                                 __HIP_MEMORY_SCOPE_WORKGROUP);              \
        if (seen < need) __builtin_amdgcn_s_sleep(1);                        \
      }                                                                      \
    }                                                                        \
    float4 cb = make_float4(BIGF, BIGF, BIGF, BIGF);                         \
    if (w > 0 && sw_ < NQ) cb = buf_s[(w - 1) * NQ + sw_];                   \
    float na0 = __shfl_up(vD0, 1, 64);                                       \
    float na1 = __shfl_up(vD1, 1, 64);                                       \
    float na2 = __shfl_up(vD2, 1, 64);                                       \
    float na3 = __shfl_up(vD3, 1, 64);                                       \
    const float a0 = (lane == 0) ? cb.x : na0;                               \
    const float a1 = (lane == 0) ? cb.y : na1;                               \
    const float a2 = (lane == 0) ? cb.z : na2;                               \
    const float a3 = (lane == 0) ? cb.w : na3;                               \
    const int q = sw_ - lane;                                                \
    { /* prefetch tile(s+2) into TC (clamped; junk-safe) */                  \
      int qn = sw_ + 2 - lane;                                               \
      qn = qn < 0 ? 0 : (qn > NQ - 1 ? NQ - 1 : qn);                         \
      const float4* bp = &tgt4_s[qn * 9];                                    \
      TC[0] = bp[0]; TC[1] = bp[1]; TC[2] = bp[2]; TC[3] = bp[3];            \
      TC[4] = bp[4]; TC[5] = bp[5]; TC[6] = bp[6]; TC[7] = bp[7];            \
      TC[8] = bp[8];                                                         \
    }                                                                        \
    { /* dots(s+1) from TN (independent work, fills the chain stall) */      \
      const float4 nr = TN[8];                                               \
      v2f s_;                                                                \
      s_.x = pnA + nr.x; s_.y = pnA + nr.y; DN[0] = dot8h<false>(s_, ppA, TN); \
      s_.x = pnA + nr.z; s_.y = pnA + nr.w; DN[1] = dot8h<true>(s_, ppA, TN);  \
      s_.x = pnB + nr.x; s_.y = pnB + nr.y; DN[2] = dot8h<false>(s_, ppB, TN); \
      s_.x = pnB + nr.z; s_.y = pnB + nr.w; DN[3] = dot8h<true>(s_, ppB, TN);  \
      s_.x = pnC + nr.x; s_.y = pnC + nr.y; DN[4] = dot8h<false>(s_, ppC, TN); \
      s_.x = pnC + nr.z; s_.y = pnC + nr.w; DN[5] = dot8h<true>(s_, ppC, TN);  \
      s_.x = pnD + nr.x; s_.y = pnD + nr.y; DN[6] = dot8h<false>(s_, ppD, TN); \
      s_.x = pnD + nr.z; s_.y = pnD + nr.w; DN[7] = dot8h<true>(s_, ppD, TN);  \
    }                                                                        \
    if (q >= 0 && q < NQ) {                                                  \
      float vA0 = DC[0].x + softmin2(carry, a0, lA);                         \
      float vA1 = DC[0].y + softmin2(a0, a1, vA0);                           \
      float vA2 = DC[1].x + softmin2(a1, a2, vA1);                           \
      float vA3 = DC[1].y + softmin2(a2, a3, vA2);                           \
      float vB0 = DC[2].x + softmin2(lA, vA0, lB);                           \
      float vB1 = DC[2].y + softmin2(vA0, vA1, vB0);                         \
      float vB2 = DC[3].x + softmin2(vA1, vA2, vB1);                         \
      float vB3 = DC[3].y + softmin2(vA2, vA3, vB2);                         \
      float vC0 = DC[4].x + softmin2(lB, vB0, lC);                           \
      float vC1 = DC[4].y + softmin2(vB0, vB1, vC0);                         \
      float vC2 = DC[5].x + softmin2(vB1, vB2, vC1);                         \
      float vC3 = DC[5].y + softmin2(vB2, vB3, vC2);                         \
      vD0 = DC[6].x + softmin2(lC, vC0, lD);                                 \
      vD1 = DC[6].y + softmin2(vC0, vC1, vD0);                               \
      vD2 = DC[7].x + softmin2(vC1, vC2, vD1);                               \
      vD3 = DC[7].y + softmin2(vC2, vC3, vD2);                               \
      lA = vA3; lB = vB3; lC = vC3; lD = vD3; carry = a3;                    \
      if (lane == 63 && w < NW - 1)                                          \
        buf_s[w * NQ + q] = make_float4(vD0, vD1, vD2, vD3);                 \
      if (t == NTH - 1 && q == NQ - 1) ws[b] = vD3 * LN2F;                   \
    }                                                                        \
    if (lane == 63 && w < NW - 1 && ((sw_ & 7) == 7 || sw_ == WSTEPS - 1))   \
      __hip_atomic_store(&prog_s[w], sw_, __ATOMIC_RELEASE,                  \
                         __HIP_MEMORY_SCOPE_WORKGROUP);                      \
  }

__global__ __launch_bounds__(NTH, 1) void sdtw_kernel(const float* __restrict__ pred,
                                                      const float* __restrict__ target,
                                                      float* __restrict__ ws) {
  __shared__ float4 tgt4_s[NQ * 9];       // 36 KiB: 8 dim-chunks + norms per tile
  __shared__ float4 buf_s[(NW - 1) * NQ]; // 12 KiB handoff (bottom rows)
  __shared__ int prog_s[NW];

  const int t    = threadIdx.x;
  const int w    = t >> 6;
  const int lane = t & 63;
  const int b    = blockIdx.x;
  const float* pr = pred + (size_t)b * T * 8;
  const float* tg = target + (size_t)b * T * 8;

  // ---- stage target: thread t stages tile t (target rows 4t..4t+3) --------
  // chunk m (m=0..7) = dim m over the 4 rows, scaled by -2*log2e;
  // chunk 8 = (|r0|^2,|r1|^2,|r2|^2,|r3|^2) * log2e.
  {
    const float4* tg4 = reinterpret_cast<const float4*>(tg);
    float4 u00 = tg4[t * 8 + 0], u01 = tg4[t * 8 + 1];
    float4 u10 = tg4[t * 8 + 2], u11 = tg4[t * 8 + 3];
    float4 u20 = tg4[t * 8 + 4], u21 = tg4[t * 8 + 5];
    float4 u30 = tg4[t * 8 + 6], u31 = tg4[t * 8 + 7];
#define NRM1(a, bq)                                                          \
  (((a.x * a.x + a.y * a.y) + (a.z * a.z + a.w * a.w) +                      \
    (bq.x * bq.x + bq.y * bq.y) + (bq.z * bq.z + bq.w * bq.w)))
    float n0 = NRM1(u00, u01), n1 = NRM1(u10, u11);
    float n2 = NRM1(u20, u21), n3 = NRM1(u30, u31);
    const float s = -2.0f * L2EF;
    float4* dst = &tgt4_s[t * 9];
    dst[0] = make_float4(u00.x * s, u10.x * s, u20.x * s, u30.x * s);
    dst[1] = make_float4(u00.y * s, u10.y * s, u20.y * s, u30.y * s);
    dst[2] = make_float4(u00.z * s, u10.z * s, u20.z * s, u30.z * s);
    dst[3] = make_float4(u00.w * s, u10.w * s, u20.w * s, u30.w * s);
    dst[4] = make_float4(u01.x * s, u11.x * s, u21.x * s, u31.x * s);
    dst[5] = make_float4(u01.y * s, u11.y * s, u21.y * s, u31.y * s);
    dst[6] = make_float4(u01.z * s, u11.z * s, u21.z * s, u31.z * s);
    dst[7] = make_float4(u01.w * s, u11.w * s, u21.w * s, u31.w * s);
    dst[8] = make_float4(n0 * L2EF, n1 * L2EF, n2 * L2EF, n3 * L2EF);
  }
  if (t < NW) prog_s[t] = -1;

  // ---- pred rows 4t..4t+3 -> pair registers + scaled norms ----------------
  const float4* pr4 = reinterpret_cast<const float4*>(pr);
  float4 qA0 = pr4[t * 8 + 0], qA1 = pr4[t * 8 + 1];
  float4 qB0 = pr4[t * 8 + 2], qB1 = pr4[t * 8 + 3];
  float4 qC0 = pr4[t * 8 + 4], qC1 = pr4[t * 8 + 5];
  float4 qD0 = pr4[t * 8 + 6], qD1 = pr4[t * 8 + 7];
  float pnA = NRM1(qA0, qA1) * L2EF, pnB = NRM1(qB0, qB1) * L2EF;
  float pnC = NRM1(qC0, qC1) * L2EF, pnD = NRM1(qD0, qD1) * L2EF;
#define PAIRS(pp, r0, r1)                                                    \
  pp[0] = lo2(r0); pp[1] = hi2(r0); pp[2] = lo2(r1); pp[3] = hi2(r1);
  v2f ppA[4], ppB[4], ppC[4], ppD[4];
  PAIRS(ppA, qA0, qA1) PAIRS(ppB, qB0, qB1)
  PAIRS(ppC, qC0, qC1) PAIRS(ppD, qD0, qD1)

  __syncthreads(); // staging complete (only block-wide barrier)

  // ---- DP state ------------------------------------------------------------
  float lA = BIGF, lB = BIGF, lC = BIGF, lD = BIGF;
  float carry = (t == 0) ? 0.0f : BIGF;
  float vD0 = BIGF, vD1 = BIGF, vD2 = BIGF, vD3 = BIGF;
  int seen = -1;

  float4 tA[9], tB[9];
  v2f dA[8], dB[8];
  { // prologue: tile(0)->tA, tile(1)->tB, dots(0)->dA
    const float4* bp = &tgt4_s[0]; // all lanes clamp q=0
    tA[0] = bp[0]; tA[1] = bp[1]; tA[2] = bp[2]; tA[3] = bp[3];
    tA[4] = bp[4]; tA[5] = bp[5]; tA[6] = bp[6]; tA[7] = bp[7]; tA[8] = bp[8];
    int q1 = 1 - lane; q1 = q1 < 0 ? 0 : q1;
    const float4* bq = &tgt4_s[q1 * 9];
    tB[0] = bq[0]; tB[1] = bq[1]; tB[2] = bq[2]; tB[3] = bq[3];
    tB[4] = bq[4]; tB[5] = bq[5]; tB[6] = bq[6]; tB[7] = bq[7]; tB[8] = bq[8];
    const float4 nr = tA[8];
    v2f s_;
    s_.x = pnA + nr.x; s_.y = pnA + nr.y; dA[0] = dot8h<false>(s_, ppA, tA);
    s_.x = pnA + nr.z; s_.y = pnA + nr.w; dA[1] = dot8h<true>(s_, ppA, tA);
    s_.x = pnB + nr.x; s_.y = pnB + nr.y; dA[2] = dot8h<false>(s_, ppB, tA);
    s_.x = pnB + nr.z; s_.y = pnB + nr.w; dA[3] = dot8h<true>(s_, ppB, tA);
    s_.x = pnC + nr.x; s_.y = pnC + nr.y; dA[4] = dot8h<false>(s_, ppC, tA);
    s_.x = pnC + nr.z; s_.y = pnC + nr.w; dA[5] = dot8h<true>(s_, ppC, tA);
    s_.x = pnD + nr.x; s_.y = pnD + nr.y; dA[6] = dot8h<false>(s_, ppD, tA);
    s_.x = pnD + nr.z; s_.y = pnD + nr.w; dA[7] = dot8h<true>(s_, ppD, tA);
  }

  for (int sw = 0; sw < 320; sw += 2) { // 320 >= WSTEPS; extra step inert
    STEP(sw, tA, tB, dA, dB)
    STEP(sw + 1, tB, tA, dB, dA)
  }
}

__global__ void sdtw_reduce(const float* __restrict__ ws, float* __restrict__ out) {
  int l = threadIdx.x; // 64 threads = one wave
  float v = ws[l];
#pragma unroll
  for (int k = 32; k >= 1; k >>= 1) v += __shfl_down(v, k, 64);
  if (l == 0) out[0] = v * (1.0f / (float)NB);
}

extern "C" void kernel_launch(void* const* d_in, const int* in_sizes, int n_in,
                              void* d_out, int out_size, void* d_ws, size_t ws_size,
                              hipStream_t stream) {
  const float* pred   = (const float*)d_in[0];
  const float* target = (const float*)d_in[1];
  float* out = (float*)d_out;
  float* ws  = (float*)d_ws;

  sdtw_kernel<<<NB, NTH, 0, stream>>>(pred, target, ws);
  sdtw_reduce<<<1, 64, 0, stream>>>(ws, out);
}